// Round 8
// baseline (722.156 us; speedup 1.0000x reference)
//
#include <hip/hip_runtime.h>

// SAGE_Net: 2-layer GraphSAGE, N=100k, E=1.6M, 128->128->64, fp32.
// R8: plane layouts restored (contiguous MFMA fragment loads) + fused
// GEMM1->GEMM2 with h kept in REGISTERS (shfl_xor(32) assembles GEMM2's
// B fragments; no LDS, no barriers). x row-major copy deleted: gathers
// read 16B granules straight from x planes.

typedef unsigned int uint32;
typedef short bf16x4 __attribute__((ext_vector_type(4)));
typedef short bf16x8 __attribute__((ext_vector_type(8)));
typedef float f32x16 __attribute__((ext_vector_type(16)));

__device__ __forceinline__ uint32 pack_bf16_rne(float a, float b) {
    uint32 ua = __float_as_uint(a);
    uint32 ub = __float_as_uint(b);
    uint32 ra = (ua + 0x7fffu + ((ua >> 16) & 1u)) >> 16;
    uint32 rb = (ub + 0x7fffu + ((ub >> 16) & 1u)) >> 16;
    return ra | (rb << 16);
}
__device__ __forceinline__ float bf_lo(uint32 v) { return __uint_as_float(v << 16); }
__device__ __forceinline__ float bf_hi(uint32 v) { return __uint_as_float(v & 0xffff0000u); }

__device__ __forceinline__ short rne16(float v, float* back) {
    uint32 u = __float_as_uint(v);
    uint32 r = (u + 0x7fffu + ((u >> 16) & 1u)) >> 16;
    *back = __uint_as_float(r << 16);
    return (short)r;
}

__device__ __forceinline__ bf16x8 mk_bf8(uint2 lo, uint2 hi) {
    union { uint4 u; bf16x8 v; } cv;
    cv.u.x = lo.x; cv.u.y = lo.y; cv.u.z = hi.x; cv.u.w = hi.y;
    return cv.v;
}
__device__ __forceinline__ uint2 shfl32_u2(uint2 v) {
    uint2 r;
    r.x = __shfl_xor(v.x, 32);
    r.y = __shfl_xor(v.y, 32);
    return r;
}

// ---- prep: x -> x planes (bf16 hi); weights -> hi/lo planes ----
// plane c of x: k=8c..8c+7, 8 shorts per node, stride spl shorts.
// W1 planes: 32 planes stride 1024 shorts (K=256: k<128 W1l, else W1r).
// W2 planes: 16 planes stride 1024 (rows j<64 -> W2l, else W2r).
__global__ void k_prep(const float* __restrict__ x, short* __restrict__ xpH,
                       long n4, int spl,
                       const float* __restrict__ W1l, const float* __restrict__ W1r,
                       const float* __restrict__ W2l, const float* __restrict__ W2r,
                       short* __restrict__ W1pH, short* __restrict__ W1pL,
                       short* __restrict__ W2pH, short* __restrict__ W2pL) {
    long i = (long)blockIdx.x * blockDim.x + threadIdx.x;
    float back;
    if (i < n4) {
        int node = (int)(i >> 5);
        int k4 = ((int)i & 31) * 4;
        float4 v = ((const float4*)x)[i];
        bf16x4 hi4;
        hi4[0] = rne16(v.x, &back);
        hi4[1] = rne16(v.y, &back);
        hi4[2] = rne16(v.z, &back);
        hi4[3] = rne16(v.w, &back);
        int c = k4 >> 3;
        *(bf16x4*)&xpH[(size_t)c * spl + (size_t)node * 8 + (k4 & 7)] = hi4;
        return;
    }
    int i2 = (int)(i - n4);
    if (i2 < 32768) {
        int j = i2 >> 8, k = i2 & 255;
        float v = (k < 128) ? W1l[j * 128 + k] : W1r[j * 128 + k - 128];
        float hb;
        short hs = rne16(v, &hb);
        short ls = rne16(v - hb, &back);
        int idx = (k >> 3) * 1024 + j * 8 + (k & 7);
        W1pH[idx] = hs;
        W1pL[idx] = ls;
    } else if (i2 < 32768 + 16384) {
        int i3 = i2 - 32768;
        int j = i3 >> 7, k = i3 & 127;
        float v = (j < 64) ? W2l[j * 128 + k] : W2r[(j - 64) * 128 + k];
        float hb;
        short hs = rne16(v, &hb);
        short ls = rne16(v - hb, &back);
        int idx = (k >> 3) * 1024 + j * 8 + (k & 7);
        W2pH[idx] = hs;
        W2pL[idx] = ls;
    }
}

// ---- bucketed CSR build (unchanged) ----

__global__ void k_bcount(const int* __restrict__ ei, int E, int NB,
                         int* __restrict__ bucket_cnt) {
    __shared__ int hist[1024];
    int t = threadIdx.x;
    for (int i = t; i < NB; i += 256) hist[i] = 0;
    __syncthreads();
    int stride = gridDim.x * 256;
    for (int e = blockIdx.x * 256 + t; e < E; e += stride)
        atomicAdd(&hist[ei[E + e] >> 8], 1);
    __syncthreads();
    for (int i = t; i < NB; i += 256) {
        int c = hist[i];
        if (c) atomicAdd(&bucket_cnt[i], c);
    }
}

__global__ void k_bscan(const int* __restrict__ bucket_cnt, int NB, int E,
                        int* __restrict__ bucket_off, int* __restrict__ bucket_cur) {
    __shared__ int s[1024];
    int t = threadIdx.x;
    int v = (t < NB) ? bucket_cnt[t] : 0;
    s[t] = v;
    __syncthreads();
    for (int o = 1; o < 1024; o <<= 1) {
        int u = (t >= o) ? s[t - o] : 0;
        __syncthreads();
        s[t] += u;
        __syncthreads();
    }
    int ex = s[t] - v;
    if (t < NB) { bucket_off[t] = ex; bucket_cur[t] = ex; }
    if (t == NB - 1) bucket_off[NB] = ex + v;
}

__global__ void k_bscatter(const int* __restrict__ ei, int E, int NB,
                           int* __restrict__ bucket_cur, uint32* __restrict__ eb) {
    __shared__ int hist[1024];
    __shared__ int base[1024];
    int t = threadIdx.x;
    for (int i = t; i < NB; i += 256) hist[i] = 0;
    __syncthreads();
    int stride = gridDim.x * 256;
    for (int e = blockIdx.x * 256 + t; e < E; e += stride)
        atomicAdd(&hist[ei[E + e] >> 8], 1);
    __syncthreads();
    for (int i = t; i < NB; i += 256) {
        int c = hist[i];
        base[i] = c ? atomicAdd(&bucket_cur[i], c) : 0;
        hist[i] = 0;
    }
    __syncthreads();
    for (int e = blockIdx.x * 256 + t; e < E; e += stride) {
        int d = ei[E + e];
        int b = d >> 8;
        int r = atomicAdd(&hist[b], 1);
        eb[base[b] + r] = ((uint32)(d & 255) << 24) | (uint32)ei[e];
    }
}

__global__ void k_bfinal(const uint32* __restrict__ eb,
                         const int* __restrict__ bucket_off,
                         int* __restrict__ row_ptr, int* __restrict__ col,
                         int N, int E) {
    __shared__ int deg[256];
    __shared__ int sc[256];
    __shared__ int cur[256];
    int b = blockIdx.x;
    int t = threadIdx.x;
    int beg = bucket_off[b], end = bucket_off[b + 1];
    deg[t] = 0;
    __syncthreads();
    for (int e = beg + t; e < end; e += 256)
        atomicAdd(&deg[eb[e] >> 24], 1);
    __syncthreads();
    int v = deg[t];
    sc[t] = v;
    __syncthreads();
    for (int o = 1; o < 256; o <<= 1) {
        int u = (t >= o) ? sc[t - o] : 0;
        __syncthreads();
        sc[t] += u;
        __syncthreads();
    }
    int ex = sc[t] - v;
    int node = b * 256 + t;
    if (node < N) row_ptr[node] = beg + ex;
    if (b == gridDim.x - 1 && t == 0) row_ptr[N] = E;
    cur[t] = ex;
    __syncthreads();
    for (int e = beg + t; e < end; e += 256) {
        uint32 u = eb[e];
        int r = atomicAdd(&cur[u >> 24], 1);
        col[beg + r] = (int)(u & 0xFFFFFFu);
    }
}

// ---- aggregation 1: gather 16B granules from x planes, emit mean planes ----
// wave per node; subgroup g (of 4, 16 lanes), f = lane&15 = plane index.

__global__ void k_agg_mean(const int* __restrict__ rp, const int* __restrict__ col,
                           const uint32* __restrict__ xpH,
                           short* __restrict__ mpH, short* __restrict__ mpL,
                           int N, int Np, int spl) {
    int node = blockIdx.x * 4 + (threadIdx.x >> 6);
    if (node >= N) return;
    node = __builtin_amdgcn_readfirstlane(node);
    int lane = threadIdx.x & 63;
    int g = lane >> 4;
    int f = lane & 15;
    int beg = rp[node], end = rp[node + 1];
    const uint4* xp4 = (const uint4*)xpH;  // plane f: Np uint4s
    size_t pbase = (size_t)f * Np;
    float s[8];
#pragma unroll
    for (int j = 0; j < 8; j++) s[j] = 0.f;

#define ACC_RAW(v)                                                      \
    { s[0] += bf_lo(v.x); s[1] += __uint_as_float(v.x);                 \
      s[2] += bf_lo(v.y); s[3] += __uint_as_float(v.y);                 \
      s[4] += bf_lo(v.z); s[5] += __uint_as_float(v.z);                 \
      s[6] += bf_lo(v.w); s[7] += __uint_as_float(v.w); }

    int e = beg;
    for (; e + 16 <= end; e += 16) {
        uint4 cv = *(const uint4*)(col + e + 4 * g);
        uint4 v0 = xp4[pbase + cv.x];
        uint4 v1 = xp4[pbase + cv.y];
        uint4 v2 = xp4[pbase + cv.z];
        uint4 v3 = xp4[pbase + cv.w];
        ACC_RAW(v0); ACC_RAW(v1); ACC_RAW(v2); ACC_RAW(v3);
    }
    for (; e + 8 <= end; e += 8) {
        uint2 cv = *(const uint2*)(col + e + 2 * g);
        uint4 v0 = xp4[pbase + cv.x];
        uint4 v1 = xp4[pbase + cv.y];
        ACC_RAW(v0); ACC_RAW(v1);
    }
    int rem = end - e;
    if (2 * g < rem) {
        uint4 v0 = xp4[pbase + col[e + 2 * g]];
        ACC_RAW(v0);
    }
    if (2 * g + 1 < rem) {
        uint4 v0 = xp4[pbase + col[e + 2 * g + 1]];
        ACC_RAW(v0);
    }
#undef ACC_RAW
#pragma unroll
    for (int j = 0; j < 8; j++) {
        s[j] += __shfl_xor(s[j], 16);
        s[j] += __shfl_xor(s[j], 32);
    }
    if (g == 0) {
        float inv = 1.0f / (float)max(end - beg, 1);
        uint32 H[4], L[4];
#pragma unroll
        for (int p = 0; p < 4; p++) {
            float m0 = s[2 * p] * inv, m1 = s[2 * p + 1] * inv;
            float b;
            short h0 = rne16(m0, &b);
            short l0 = rne16(m0 - b, &b);
            short h1 = rne16(m1, &b);
            short l1 = rne16(m1 - b, &b);
            H[p] = (uint32)(unsigned short)h0 | ((uint32)(unsigned short)h1 << 16);
            L[p] = (uint32)(unsigned short)l0 | ((uint32)(unsigned short)l1 << 16);
        }
        size_t idx = (size_t)f * spl + (size_t)node * 8;
        *(uint4*)&mpH[idx] = make_uint4(H[0], H[1], H[2], H[3]);
        *(uint4*)&mpL[idx] = make_uint4(L[0], L[1], L[2], L[3]);
    }
}

// ---- fused transposed MFMA GEMMs, register h, no LDS ----
// GEMM1: A=W1 planes (lane m -> j), B=act planes (lane m -> node);
// C col = node (lane-fixed), rows = j. h stays in registers (lane holds
// j&7 in {4hh..4hh+3} of all 16 planes for its node; partner lane^32 holds
// the rest). GEMM2 B fragments assembled via shfl_xor(32).

__global__ __launch_bounds__(256) void k_mgemm(
        const short* __restrict__ mpH, const short* __restrict__ mpL,
        const short* __restrict__ xpH,
        const short* __restrict__ W1pH, const short* __restrict__ W1pL,
        const short* __restrict__ W2pH, const short* __restrict__ W2pL,
        const float* __restrict__ b1, const float* __restrict__ b2,
        unsigned short* __restrict__ hl, float* __restrict__ hr, int N, int spl) {
    int t = threadIdx.x;
    int w = t >> 6, lane = t & 63;
    int m = lane & 31, hh = lane >> 5;
    int node0 = blockIdx.x * 128;
    int mynode = node0 + 32 * w + m;
    f32x16 acc[4];
#pragma unroll
    for (int i = 0; i < 4; i++)
#pragma unroll
        for (int r = 0; r < 16; r++) acc[i][r] = 0.f;

    // GEMM1 seg 0: mean (3-term), B-planes 0..15 of activations, W1 planes 0..15
    for (int kc = 0; kc < 8; kc++) {
        int c = 2 * kc + hh;
        bf16x8 bH = *(const bf16x8*)(mpH + (size_t)c * spl + (size_t)mynode * 8);
        bf16x8 bL = *(const bf16x8*)(mpL + (size_t)c * spl + (size_t)mynode * 8);
#pragma unroll
        for (int jt = 0; jt < 4; jt++) {
            bf16x8 aH = *(const bf16x8*)(W1pH + c * 1024 + (32 * jt + m) * 8);
            bf16x8 aL = *(const bf16x8*)(W1pL + c * 1024 + (32 * jt + m) * 8);
            acc[jt] = __builtin_amdgcn_mfma_f32_32x32x16_bf16(aH, bH, acc[jt], 0, 0, 0);
            acc[jt] = __builtin_amdgcn_mfma_f32_32x32x16_bf16(aL, bH, acc[jt], 0, 0, 0);
            acc[jt] = __builtin_amdgcn_mfma_f32_32x32x16_bf16(aH, bL, acc[jt], 0, 0, 0);
        }
    }
    // GEMM1 seg 1: x (2-term), W1 planes 16..31
    for (int kc = 0; kc < 8; kc++) {
        int c = 2 * kc + hh;
        bf16x8 bH = *(const bf16x8*)(xpH + (size_t)c * spl + (size_t)mynode * 8);
#pragma unroll
        for (int jt = 0; jt < 4; jt++) {
            bf16x8 aH = *(const bf16x8*)(W1pH + (16 + c) * 1024 + (32 * jt + m) * 8);
            bf16x8 aL = *(const bf16x8*)(W1pL + (16 + c) * 1024 + (32 * jt + m) * 8);
            acc[jt] = __builtin_amdgcn_mfma_f32_32x32x16_bf16(aH, bH, acc[jt], 0, 0, 0);
            acc[jt] = __builtin_amdgcn_mfma_f32_32x32x16_bf16(aL, bH, acc[jt], 0, 0, 0);
        }
    }
    // epilogue 1: relu + b1, split hi/lo -> registers.
    // h4H[c] = 4 bf16 of plane c (j&7 = 4hh..4hh+3) for this lane's node.
    uint2 h4H[16], h4L[16];
#pragma unroll
    for (int jt = 0; jt < 4; jt++) {
#pragma unroll
        for (int rg = 0; rg < 4; rg++) {
            int j0 = 32 * jt + 8 * rg + 4 * hh;
            int c = 4 * jt + rg;
            float4 bv = *(const float4*)(b1 + j0);
            float bb[4] = {bv.x, bv.y, bv.z, bv.w};
            short hs[4], ls[4];
#pragma unroll
            for (int q = 0; q < 4; q++) {
                float v = fmaxf(acc[jt][4 * rg + q] + bb[q], 0.f);
                float back;
                hs[q] = rne16(v, &back);
                ls[q] = rne16(v - back, &back);
            }
            h4H[c].x = (uint32)(unsigned short)hs[0] | ((uint32)(unsigned short)hs[1] << 16);
            h4H[c].y = (uint32)(unsigned short)hs[2] | ((uint32)(unsigned short)hs[3] << 16);
            h4L[c].x = (uint32)(unsigned short)ls[0] | ((uint32)(unsigned short)ls[1] << 16);
            h4L[c].y = (uint32)(unsigned short)ls[2] | ((uint32)(unsigned short)ls[3] << 16);
        }
    }
    // GEMM2: (hl|hr)^T = W2 . h^T, K=128, 3-term; B assembled via shfl.
#pragma unroll
    for (int i = 0; i < 4; i++)
#pragma unroll
        for (int r = 0; r < 16; r++) acc[i][r] = 0.f;
#pragma unroll
    for (int kc = 0; kc < 8; kc++) {
        int c = 2 * kc + hh;
        uint2 mEH = h4H[2 * kc], mOH = h4H[2 * kc + 1];
        uint2 mEL = h4L[2 * kc], mOL = h4L[2 * kc + 1];
        uint2 eEH = shfl32_u2(mEH), eOH = shfl32_u2(mOH);
        uint2 eEL = shfl32_u2(mEL), eOL = shfl32_u2(mOL);
        // lane's plane c = 2kc+hh: low4 (j&7=0..3) , high4 (j&7=4..7)
        uint2 loH = hh ? eOH : mEH;
        uint2 hiH = hh ? mOH : eEH;
        uint2 loL = hh ? eOL : mEL;
        uint2 hiL = hh ? mOL : eEL;
        bf16x8 bH = mk_bf8(loH, hiH);
        bf16x8 bL = mk_bf8(loL, hiL);
#pragma unroll
        for (int jt = 0; jt < 4; jt++) {
            bf16x8 aH = *(const bf16x8*)(W2pH + c * 1024 + (32 * jt + m) * 8);
            bf16x8 aL = *(const bf16x8*)(W2pL + c * 1024 + (32 * jt + m) * 8);
            acc[jt] = __builtin_amdgcn_mfma_f32_32x32x16_bf16(aH, bH, acc[jt], 0, 0, 0);
            acc[jt] = __builtin_amdgcn_mfma_f32_32x32x16_bf16(aL, bH, acc[jt], 0, 0, 0);
            acc[jt] = __builtin_amdgcn_mfma_f32_32x32x16_bf16(aH, bL, acc[jt], 0, 0, 0);
        }
    }
    if (mynode >= N) return;
    // epilogue 2: jt 0,1 -> hl bf16 [node][64]; jt 2,3 -> hr fp32 [node][64] + b2
#pragma unroll
    for (int jt = 0; jt < 2; jt++) {
#pragma unroll
        for (int rg = 0; rg < 4; rg++) {
            int j0 = 32 * jt + 8 * rg + 4 * hh;
            uint2 o;
            o.x = pack_bf16_rne(acc[jt][4 * rg + 0], acc[jt][4 * rg + 1]);
            o.y = pack_bf16_rne(acc[jt][4 * rg + 2], acc[jt][4 * rg + 3]);
            *(uint2*)&hl[(size_t)mynode * 64 + j0] = o;
        }
    }
#pragma unroll
    for (int jt = 2; jt < 4; jt++) {
#pragma unroll
        for (int rg = 0; rg < 4; rg++) {
            int j0 = 32 * (jt - 2) + 8 * rg + 4 * hh;
            float4 bv = *(const float4*)(b2 + j0);
            float4 o;
            o.x = acc[jt][4 * rg + 0] + bv.x;
            o.y = acc[jt][4 * rg + 1] + bv.y;
            o.z = acc[jt][4 * rg + 2] + bv.z;
            o.w = acc[jt][4 * rg + 3] + bv.w;
            *(float4*)&hr[(size_t)mynode * 64 + j0] = o;
        }
    }
}

// ---- aggregation 2: wave/node, 8 subgroups of 8 lanes (unchanged R7) ----

__global__ void k_agg_out(const int* __restrict__ rp, const int* __restrict__ col,
                          const uint32* __restrict__ hl, const float* __restrict__ hr,
                          float* __restrict__ out, int N) {
    int node = blockIdx.x * 4 + (threadIdx.x >> 6);
    if (node >= N) return;
    node = __builtin_amdgcn_readfirstlane(node);
    int lane = threadIdx.x & 63;
    int g = lane >> 3;
    int f = lane & 7;
    int beg = rp[node], end = rp[node + 1];
    const uint4* hl4 = (const uint4*)hl;  // row = 8 uint4
    float s[8];
#pragma unroll
    for (int j = 0; j < 8; j++) s[j] = 0.f;

#define ACC_MSK(v)                                          \
    { s[0] += bf_lo(v.x); s[1] += bf_hi(v.x);               \
      s[2] += bf_lo(v.y); s[3] += bf_hi(v.y);               \
      s[4] += bf_lo(v.z); s[5] += bf_hi(v.z);               \
      s[6] += bf_lo(v.w); s[7] += bf_hi(v.w); }

    int e = beg;
    for (; e + 16 <= end; e += 16) {
        uint2 cv = *(const uint2*)(col + e + 2 * g);
        uint4 v0 = hl4[(size_t)cv.x * 8 + f];
        uint4 v1 = hl4[(size_t)cv.y * 8 + f];
        ACC_MSK(v0); ACC_MSK(v1);
    }
    for (; e + 8 <= end; e += 8) {
        uint4 v0 = hl4[(size_t)col[e + g] * 8 + f];
        ACC_MSK(v0);
    }
    int rem = end - e;
    if (g < rem) {
        uint4 v0 = hl4[(size_t)col[e + g] * 8 + f];
        ACC_MSK(v0);
    }
#undef ACC_MSK
#pragma unroll
    for (int j = 0; j < 8; j++) {
        s[j] += __shfl_xor(s[j], 8);
        s[j] += __shfl_xor(s[j], 16);
        s[j] += __shfl_xor(s[j], 32);
    }
    if (g == 0) {
        float inv = 1.0f / (float)max(end - beg, 1);
        const float* hrp = hr + (size_t)node * 64 + f * 8;
        float4 h0 = *(const float4*)(hrp);
        float4 h1 = *(const float4*)(hrp + 4);
        float4 o0, o1;
        o0.x = s[0] * inv + h0.x;
        o0.y = s[1] * inv + h0.y;
        o0.z = s[2] * inv + h0.z;
        o0.w = s[3] * inv + h0.w;
        o1.x = s[4] * inv + h1.x;
        o1.y = s[5] * inv + h1.y;
        o1.z = s[6] * inv + h1.z;
        o1.w = s[7] * inv + h1.w;
        float* op = out + (size_t)node * 64 + f * 8;
        *(float4*)(op) = o0;
        *(float4*)(op + 4) = o1;
    }
}

extern "C" void kernel_launch(void* const* d_in, const int* in_sizes, int n_in,
                              void* d_out, int out_size, void* d_ws, size_t ws_size,
                              hipStream_t stream) {
    const float* x   = (const float*)d_in[0];
    const float* W1l = (const float*)d_in[1];
    const float* W1r = (const float*)d_in[2];
    const float* b1  = (const float*)d_in[3];
    const float* W2l = (const float*)d_in[4];
    const float* W2r = (const float*)d_in[5];
    const float* b2  = (const float*)d_in[6];
    const int*   ei  = (const int*)d_in[7];
    int N = in_sizes[0] / 128;
    int E = in_sizes[7] / 2;
    int NB = (N + 255) >> 8;
    int gb = (N + 127) / 128;
    int Np = gb * 128;      // padded node count for planes
    int spl = Np * 8;       // plane stride in shorts
    float* out = (float*)d_out;

    char* w = (char*)d_ws;
    size_t off = 0;
    auto alloc = [&](size_t bytes) -> char* {
        char* p = w + off;
        off += (bytes + 255) & ~(size_t)255;
        return p;
    };
    int*   row_ptr = (int*)alloc((size_t)(N + 1) * 4);
    int*   bcnt    = (int*)alloc((size_t)(NB + 1) * 4);
    int*   boff    = (int*)alloc((size_t)(NB + 1) * 4);
    int*   bcur    = (int*)alloc((size_t)(NB + 1) * 4);
    short* W1pH    = (short*)alloc(32768 * 2);
    short* W1pL    = (short*)alloc(32768 * 2);
    short* W2pH    = (short*)alloc(16384 * 2);
    short* W2pL    = (short*)alloc(16384 * 2);
    int*   col     = (int*)alloc((size_t)E * 4);
    short* xpH     = (short*)alloc((size_t)16 * spl * 2);   // 25.6 MB
    short* mpH     = (short*)alloc((size_t)16 * spl * 2);   // 25.6 MB
    short* mpL     = (short*)alloc((size_t)16 * spl * 2);   // 25.6 MB
    unsigned short* hl = (unsigned short*)alloc((size_t)N * 64 * 2);  // 12.8 MB
    float* hr      = (float*)alloc((size_t)N * 64 * 4);     // 25.6 MB
    uint32* eb     = (uint32*)hl;  // dead after k_bfinal; hl written by k_mgemm

    hipMemsetAsync(bcnt, 0, (size_t)NB * 4, stream);
    long n4 = (long)N * 32;
    long prep_items = n4 + 32768 + 16384;
    k_prep<<<(int)((prep_items + 255) / 256), 256, 0, stream>>>(
        x, xpH, n4, spl, W1l, W1r, W2l, W2r, W1pH, W1pL, W2pH, W2pL);
    k_bcount<<<256, 256, 0, stream>>>(ei, E, NB, bcnt);
    k_bscan<<<1, 1024, 0, stream>>>(bcnt, NB, E, boff, bcur);
    k_bscatter<<<128, 256, 0, stream>>>(ei, E, NB, bcur, eb);
    k_bfinal<<<NB, 256, 0, stream>>>(eb, boff, row_ptr, col, N, E);

    int ab = (N + 3) / 4;
    k_agg_mean<<<ab, 256, 0, stream>>>(row_ptr, col, (const uint32*)xpH,
                                       mpH, mpL, N, Np, spl);
    k_mgemm<<<gb, 256, 0, stream>>>(mpH, mpL, xpH, W1pH, W1pL, W2pH, W2pL,
                                    b1, b2, hl, hr, N, spl);
    k_agg_out<<<ab, 256, 0, stream>>>(row_ptr, col, (const uint32*)hl, hr, out, N);
}

// Round 9
// 372.867 us; speedup vs baseline: 1.9368x; 1.9368x over previous
//
#include <hip/hip_runtime.h>

// SAGE_Net: 2-layer GraphSAGE, N=100k, E=1.6M, 128->128->64, fp32.
// R9: R8's fused register-h plane-GEMM kept; gathers restored to ROW-MAJOR
// tables (xb for layer 1, hl for layer 2) — planes are for MFMA fragment
// loads only (R8 post-mortem: plane-gather = 4x line over-fetch).

typedef unsigned int uint32;
typedef short bf16x4 __attribute__((ext_vector_type(4)));
typedef short bf16x8 __attribute__((ext_vector_type(8)));
typedef float f32x16 __attribute__((ext_vector_type(16)));

__device__ __forceinline__ uint32 pack_bf16_rne(float a, float b) {
    uint32 ua = __float_as_uint(a);
    uint32 ub = __float_as_uint(b);
    uint32 ra = (ua + 0x7fffu + ((ua >> 16) & 1u)) >> 16;
    uint32 rb = (ub + 0x7fffu + ((ub >> 16) & 1u)) >> 16;
    return ra | (rb << 16);
}
__device__ __forceinline__ float bf_lo(uint32 v) { return __uint_as_float(v << 16); }
__device__ __forceinline__ float bf_hi(uint32 v) { return __uint_as_float(v & 0xffff0000u); }

__device__ __forceinline__ short rne16(float v, float* back) {
    uint32 u = __float_as_uint(v);
    uint32 r = (u + 0x7fffu + ((u >> 16) & 1u)) >> 16;
    *back = __uint_as_float(r << 16);
    return (short)r;
}

__device__ __forceinline__ bf16x8 mk_bf8(uint2 lo, uint2 hi) {
    union { uint4 u; bf16x8 v; } cv;
    cv.u.x = lo.x; cv.u.y = lo.y; cv.u.z = hi.x; cv.u.w = hi.y;
    return cv.v;
}
__device__ __forceinline__ uint2 shfl32_u2(uint2 v) {
    uint2 r;
    r.x = __shfl_xor(v.x, 32);
    r.y = __shfl_xor(v.y, 32);
    return r;
}

// ---- prep: x -> xb (row-major packed bf16, for gathers) + xpH (planes for
// MFMA); weights -> hi/lo planes (stride 1024 shorts). ----
__global__ void k_prep(const float* __restrict__ x, uint32* __restrict__ xb,
                       short* __restrict__ xpH, long n4, int spl,
                       const float* __restrict__ W1l, const float* __restrict__ W1r,
                       const float* __restrict__ W2l, const float* __restrict__ W2r,
                       short* __restrict__ W1pH, short* __restrict__ W1pL,
                       short* __restrict__ W2pH, short* __restrict__ W2pL) {
    long i = (long)blockIdx.x * blockDim.x + threadIdx.x;
    float back;
    if (i < n4) {
        int node = (int)(i >> 5);
        int k4 = ((int)i & 31) * 4;
        float4 v = ((const float4*)x)[i];
        bf16x4 hi4;
        hi4[0] = rne16(v.x, &back);
        hi4[1] = rne16(v.y, &back);
        hi4[2] = rne16(v.z, &back);
        hi4[3] = rne16(v.w, &back);
        uint2 o;
        o.x = (uint32)(unsigned short)hi4[0] | ((uint32)(unsigned short)hi4[1] << 16);
        o.y = (uint32)(unsigned short)hi4[2] | ((uint32)(unsigned short)hi4[3] << 16);
        ((uint2*)xb)[i] = o;
        int c = k4 >> 3;
        *(bf16x4*)&xpH[(size_t)c * spl + (size_t)node * 8 + (k4 & 7)] = hi4;
        return;
    }
    int i2 = (int)(i - n4);
    if (i2 < 32768) {
        int j = i2 >> 8, k = i2 & 255;
        float v = (k < 128) ? W1l[j * 128 + k] : W1r[j * 128 + k - 128];
        float hb;
        short hs = rne16(v, &hb);
        short ls = rne16(v - hb, &back);
        int idx = (k >> 3) * 1024 + j * 8 + (k & 7);
        W1pH[idx] = hs;
        W1pL[idx] = ls;
    } else if (i2 < 32768 + 16384) {
        int i3 = i2 - 32768;
        int j = i3 >> 7, k = i3 & 127;
        float v = (j < 64) ? W2l[j * 128 + k] : W2r[(j - 64) * 128 + k];
        float hb;
        short hs = rne16(v, &hb);
        short ls = rne16(v - hb, &back);
        int idx = (k >> 3) * 1024 + j * 8 + (k & 7);
        W2pH[idx] = hs;
        W2pL[idx] = ls;
    }
}

// ---- bucketed CSR build (unchanged) ----

__global__ void k_bcount(const int* __restrict__ ei, int E, int NB,
                         int* __restrict__ bucket_cnt) {
    __shared__ int hist[1024];
    int t = threadIdx.x;
    for (int i = t; i < NB; i += 256) hist[i] = 0;
    __syncthreads();
    int stride = gridDim.x * 256;
    for (int e = blockIdx.x * 256 + t; e < E; e += stride)
        atomicAdd(&hist[ei[E + e] >> 8], 1);
    __syncthreads();
    for (int i = t; i < NB; i += 256) {
        int c = hist[i];
        if (c) atomicAdd(&bucket_cnt[i], c);
    }
}

__global__ void k_bscan(const int* __restrict__ bucket_cnt, int NB, int E,
                        int* __restrict__ bucket_off, int* __restrict__ bucket_cur) {
    __shared__ int s[1024];
    int t = threadIdx.x;
    int v = (t < NB) ? bucket_cnt[t] : 0;
    s[t] = v;
    __syncthreads();
    for (int o = 1; o < 1024; o <<= 1) {
        int u = (t >= o) ? s[t - o] : 0;
        __syncthreads();
        s[t] += u;
        __syncthreads();
    }
    int ex = s[t] - v;
    if (t < NB) { bucket_off[t] = ex; bucket_cur[t] = ex; }
    if (t == NB - 1) bucket_off[NB] = ex + v;
}

__global__ void k_bscatter(const int* __restrict__ ei, int E, int NB,
                           int* __restrict__ bucket_cur, uint32* __restrict__ eb) {
    __shared__ int hist[1024];
    __shared__ int base[1024];
    int t = threadIdx.x;
    for (int i = t; i < NB; i += 256) hist[i] = 0;
    __syncthreads();
    int stride = gridDim.x * 256;
    for (int e = blockIdx.x * 256 + t; e < E; e += stride)
        atomicAdd(&hist[ei[E + e] >> 8], 1);
    __syncthreads();
    for (int i = t; i < NB; i += 256) {
        int c = hist[i];
        base[i] = c ? atomicAdd(&bucket_cur[i], c) : 0;
        hist[i] = 0;
    }
    __syncthreads();
    for (int e = blockIdx.x * 256 + t; e < E; e += stride) {
        int d = ei[E + e];
        int b = d >> 8;
        int r = atomicAdd(&hist[b], 1);
        eb[base[b] + r] = ((uint32)(d & 255) << 24) | (uint32)ei[e];
    }
}

__global__ void k_bfinal(const uint32* __restrict__ eb,
                         const int* __restrict__ bucket_off,
                         int* __restrict__ row_ptr, int* __restrict__ col,
                         int N, int E) {
    __shared__ int deg[256];
    __shared__ int sc[256];
    __shared__ int cur[256];
    int b = blockIdx.x;
    int t = threadIdx.x;
    int beg = bucket_off[b], end = bucket_off[b + 1];
    deg[t] = 0;
    __syncthreads();
    for (int e = beg + t; e < end; e += 256)
        atomicAdd(&deg[eb[e] >> 24], 1);
    __syncthreads();
    int v = deg[t];
    sc[t] = v;
    __syncthreads();
    for (int o = 1; o < 256; o <<= 1) {
        int u = (t >= o) ? sc[t - o] : 0;
        __syncthreads();
        sc[t] += u;
        __syncthreads();
    }
    int ex = sc[t] - v;
    int node = b * 256 + t;
    if (node < N) row_ptr[node] = beg + ex;
    if (b == gridDim.x - 1 && t == 0) row_ptr[N] = E;
    cur[t] = ex;
    __syncthreads();
    for (int e = beg + t; e < end; e += 256) {
        uint32 u = eb[e];
        int r = atomicAdd(&cur[u >> 24], 1);
        col[beg + r] = (int)(u & 0xFFFFFFu);
    }
}

// ---- aggregation 1: ROW-MAJOR gather from xb, vector col loads, raw-hi
// accumulate; emit mean hi/lo planes. wave/node, g=lane>>4, f=lane&15. ----

__global__ void k_agg_mean(const int* __restrict__ rp, const int* __restrict__ col,
                           const uint32* __restrict__ xb,
                           short* __restrict__ mpH, short* __restrict__ mpL,
                           int N, int spl) {
    int node = blockIdx.x * 4 + (threadIdx.x >> 6);
    if (node >= N) return;
    node = __builtin_amdgcn_readfirstlane(node);
    int lane = threadIdx.x & 63;
    int g = lane >> 4;
    int f = lane & 15;
    int beg = rp[node], end = rp[node + 1];
    const uint4* xb4 = (const uint4*)xb;  // row = 16 uint4
    float s[8];
#pragma unroll
    for (int j = 0; j < 8; j++) s[j] = 0.f;

#define ACC_RAW(v)                                                      \
    { s[0] += bf_lo(v.x); s[1] += __uint_as_float(v.x);                 \
      s[2] += bf_lo(v.y); s[3] += __uint_as_float(v.y);                 \
      s[4] += bf_lo(v.z); s[5] += __uint_as_float(v.z);                 \
      s[6] += bf_lo(v.w); s[7] += __uint_as_float(v.w); }

    int e = beg;
    for (; e + 16 <= end; e += 16) {
        uint4 cv = *(const uint4*)(col + e + 4 * g);
        uint4 v0 = xb4[(size_t)cv.x * 16 + f];
        uint4 v1 = xb4[(size_t)cv.y * 16 + f];
        uint4 v2 = xb4[(size_t)cv.z * 16 + f];
        uint4 v3 = xb4[(size_t)cv.w * 16 + f];
        ACC_RAW(v0); ACC_RAW(v1); ACC_RAW(v2); ACC_RAW(v3);
    }
    for (; e + 8 <= end; e += 8) {
        uint2 cv = *(const uint2*)(col + e + 2 * g);
        uint4 v0 = xb4[(size_t)cv.x * 16 + f];
        uint4 v1 = xb4[(size_t)cv.y * 16 + f];
        ACC_RAW(v0); ACC_RAW(v1);
    }
    int rem = end - e;
    if (2 * g < rem) {
        uint4 v0 = xb4[(size_t)col[e + 2 * g] * 16 + f];
        ACC_RAW(v0);
    }
    if (2 * g + 1 < rem) {
        uint4 v0 = xb4[(size_t)col[e + 2 * g + 1] * 16 + f];
        ACC_RAW(v0);
    }
#undef ACC_RAW
#pragma unroll
    for (int j = 0; j < 8; j++) {
        s[j] += __shfl_xor(s[j], 16);
        s[j] += __shfl_xor(s[j], 32);
    }
    if (g == 0) {
        float inv = 1.0f / (float)max(end - beg, 1);
        uint32 H[4], L[4];
#pragma unroll
        for (int p = 0; p < 4; p++) {
            float m0 = s[2 * p] * inv, m1 = s[2 * p + 1] * inv;
            float b;
            short h0 = rne16(m0, &b);
            short l0 = rne16(m0 - b, &b);
            short h1 = rne16(m1, &b);
            short l1 = rne16(m1 - b, &b);
            H[p] = (uint32)(unsigned short)h0 | ((uint32)(unsigned short)h1 << 16);
            L[p] = (uint32)(unsigned short)l0 | ((uint32)(unsigned short)l1 << 16);
        }
        size_t idx = (size_t)f * spl + (size_t)node * 8;
        *(uint4*)&mpH[idx] = make_uint4(H[0], H[1], H[2], H[3]);
        *(uint4*)&mpL[idx] = make_uint4(L[0], L[1], L[2], L[3]);
    }
}

// ---- fused transposed MFMA GEMMs, register h, no LDS (unchanged R8) ----

__global__ __launch_bounds__(256) void k_mgemm(
        const short* __restrict__ mpH, const short* __restrict__ mpL,
        const short* __restrict__ xpH,
        const short* __restrict__ W1pH, const short* __restrict__ W1pL,
        const short* __restrict__ W2pH, const short* __restrict__ W2pL,
        const float* __restrict__ b1, const float* __restrict__ b2,
        unsigned short* __restrict__ hl, float* __restrict__ hr, int N, int spl) {
    int t = threadIdx.x;
    int w = t >> 6, lane = t & 63;
    int m = lane & 31, hh = lane >> 5;
    int node0 = blockIdx.x * 128;
    int mynode = node0 + 32 * w + m;
    f32x16 acc[4];
#pragma unroll
    for (int i = 0; i < 4; i++)
#pragma unroll
        for (int r = 0; r < 16; r++) acc[i][r] = 0.f;

    for (int kc = 0; kc < 8; kc++) {
        int c = 2 * kc + hh;
        bf16x8 bH = *(const bf16x8*)(mpH + (size_t)c * spl + (size_t)mynode * 8);
        bf16x8 bL = *(const bf16x8*)(mpL + (size_t)c * spl + (size_t)mynode * 8);
#pragma unroll
        for (int jt = 0; jt < 4; jt++) {
            bf16x8 aH = *(const bf16x8*)(W1pH + c * 1024 + (32 * jt + m) * 8);
            bf16x8 aL = *(const bf16x8*)(W1pL + c * 1024 + (32 * jt + m) * 8);
            acc[jt] = __builtin_amdgcn_mfma_f32_32x32x16_bf16(aH, bH, acc[jt], 0, 0, 0);
            acc[jt] = __builtin_amdgcn_mfma_f32_32x32x16_bf16(aL, bH, acc[jt], 0, 0, 0);
            acc[jt] = __builtin_amdgcn_mfma_f32_32x32x16_bf16(aH, bL, acc[jt], 0, 0, 0);
        }
    }
    for (int kc = 0; kc < 8; kc++) {
        int c = 2 * kc + hh;
        bf16x8 bH = *(const bf16x8*)(xpH + (size_t)c * spl + (size_t)mynode * 8);
#pragma unroll
        for (int jt = 0; jt < 4; jt++) {
            bf16x8 aH = *(const bf16x8*)(W1pH + (16 + c) * 1024 + (32 * jt + m) * 8);
            bf16x8 aL = *(const bf16x8*)(W1pL + (16 + c) * 1024 + (32 * jt + m) * 8);
            acc[jt] = __builtin_amdgcn_mfma_f32_32x32x16_bf16(aH, bH, acc[jt], 0, 0, 0);
            acc[jt] = __builtin_amdgcn_mfma_f32_32x32x16_bf16(aL, bH, acc[jt], 0, 0, 0);
        }
    }
    // epilogue 1: relu + b1 -> register h (hi/lo), plane-sliced per lane
    uint2 h4H[16], h4L[16];
#pragma unroll
    for (int jt = 0; jt < 4; jt++) {
#pragma unroll
        for (int rg = 0; rg < 4; rg++) {
            int j0 = 32 * jt + 8 * rg + 4 * hh;
            int c = 4 * jt + rg;
            float4 bv = *(const float4*)(b1 + j0);
            float bb[4] = {bv.x, bv.y, bv.z, bv.w};
            short hs[4], ls[4];
#pragma unroll
            for (int q = 0; q < 4; q++) {
                float v = fmaxf(acc[jt][4 * rg + q] + bb[q], 0.f);
                float back;
                hs[q] = rne16(v, &back);
                ls[q] = rne16(v - back, &back);
            }
            h4H[c].x = (uint32)(unsigned short)hs[0] | ((uint32)(unsigned short)hs[1] << 16);
            h4H[c].y = (uint32)(unsigned short)hs[2] | ((uint32)(unsigned short)hs[3] << 16);
            h4L[c].x = (uint32)(unsigned short)ls[0] | ((uint32)(unsigned short)ls[1] << 16);
            h4L[c].y = (uint32)(unsigned short)ls[2] | ((uint32)(unsigned short)ls[3] << 16);
        }
    }
    // GEMM2: B fragments assembled via shfl_xor(32)
#pragma unroll
    for (int i = 0; i < 4; i++)
#pragma unroll
        for (int r = 0; r < 16; r++) acc[i][r] = 0.f;
#pragma unroll
    for (int kc = 0; kc < 8; kc++) {
        int c = 2 * kc + hh;
        uint2 mEH = h4H[2 * kc], mOH = h4H[2 * kc + 1];
        uint2 mEL = h4L[2 * kc], mOL = h4L[2 * kc + 1];
        uint2 eEH = shfl32_u2(mEH), eOH = shfl32_u2(mOH);
        uint2 eEL = shfl32_u2(mEL), eOL = shfl32_u2(mOL);
        uint2 loH = hh ? eOH : mEH;
        uint2 hiH = hh ? mOH : eEH;
        uint2 loL = hh ? eOL : mEL;
        uint2 hiL = hh ? mOL : eEL;
        bf16x8 bH = mk_bf8(loH, hiH);
        bf16x8 bL = mk_bf8(loL, hiL);
#pragma unroll
        for (int jt = 0; jt < 4; jt++) {
            bf16x8 aH = *(const bf16x8*)(W2pH + c * 1024 + (32 * jt + m) * 8);
            bf16x8 aL = *(const bf16x8*)(W2pL + c * 1024 + (32 * jt + m) * 8);
            acc[jt] = __builtin_amdgcn_mfma_f32_32x32x16_bf16(aH, bH, acc[jt], 0, 0, 0);
            acc[jt] = __builtin_amdgcn_mfma_f32_32x32x16_bf16(aL, bH, acc[jt], 0, 0, 0);
            acc[jt] = __builtin_amdgcn_mfma_f32_32x32x16_bf16(aH, bL, acc[jt], 0, 0, 0);
        }
    }
    if (mynode >= N) return;
#pragma unroll
    for (int jt = 0; jt < 2; jt++) {
#pragma unroll
        for (int rg = 0; rg < 4; rg++) {
            int j0 = 32 * jt + 8 * rg + 4 * hh;
            uint2 o;
            o.x = pack_bf16_rne(acc[jt][4 * rg + 0], acc[jt][4 * rg + 1]);
            o.y = pack_bf16_rne(acc[jt][4 * rg + 2], acc[jt][4 * rg + 3]);
            *(uint2*)&hl[(size_t)mynode * 64 + j0] = o;
        }
    }
#pragma unroll
    for (int jt = 2; jt < 4; jt++) {
#pragma unroll
        for (int rg = 0; rg < 4; rg++) {
            int j0 = 32 * (jt - 2) + 8 * rg + 4 * hh;
            float4 bv = *(const float4*)(b2 + j0);
            float4 o;
            o.x = acc[jt][4 * rg + 0] + bv.x;
            o.y = acc[jt][4 * rg + 1] + bv.y;
            o.z = acc[jt][4 * rg + 2] + bv.z;
            o.w = acc[jt][4 * rg + 3] + bv.w;
            *(float4*)&hr[(size_t)mynode * 64 + j0] = o;
        }
    }
}

// ---- aggregation 2: ROW-MAJOR gather from hl (unchanged R7/R8) ----

__global__ void k_agg_out(const int* __restrict__ rp, const int* __restrict__ col,
                          const uint32* __restrict__ hl, const float* __restrict__ hr,
                          float* __restrict__ out, int N) {
    int node = blockIdx.x * 4 + (threadIdx.x >> 6);
    if (node >= N) return;
    node = __builtin_amdgcn_readfirstlane(node);
    int lane = threadIdx.x & 63;
    int g = lane >> 3;
    int f = lane & 7;
    int beg = rp[node], end = rp[node + 1];
    const uint4* hl4 = (const uint4*)hl;  // row = 8 uint4
    float s[8];
#pragma unroll
    for (int j = 0; j < 8; j++) s[j] = 0.f;

#define ACC_MSK(v)                                          \
    { s[0] += bf_lo(v.x); s[1] += bf_hi(v.x);               \
      s[2] += bf_lo(v.y); s[3] += bf_hi(v.y);               \
      s[4] += bf_lo(v.z); s[5] += bf_hi(v.z);               \
      s[6] += bf_lo(v.w); s[7] += bf_hi(v.w); }

    int e = beg;
    for (; e + 16 <= end; e += 16) {
        uint2 cv = *(const uint2*)(col + e + 2 * g);
        uint4 v0 = hl4[(size_t)cv.x * 8 + f];
        uint4 v1 = hl4[(size_t)cv.y * 8 + f];
        ACC_MSK(v0); ACC_MSK(v1);
    }
    for (; e + 8 <= end; e += 8) {
        uint4 v0 = hl4[(size_t)col[e + g] * 8 + f];
        ACC_MSK(v0);
    }
    int rem = end - e;
    if (g < rem) {
        uint4 v0 = hl4[(size_t)col[e + g] * 8 + f];
        ACC_MSK(v0);
    }
#undef ACC_MSK
#pragma unroll
    for (int j = 0; j < 8; j++) {
        s[j] += __shfl_xor(s[j], 8);
        s[j] += __shfl_xor(s[j], 16);
        s[j] += __shfl_xor(s[j], 32);
    }
    if (g == 0) {
        float inv = 1.0f / (float)max(end - beg, 1);
        const float* hrp = hr + (size_t)node * 64 + f * 8;
        float4 h0 = *(const float4*)(hrp);
        float4 h1 = *(const float4*)(hrp + 4);
        float4 o0, o1;
        o0.x = s[0] * inv + h0.x;
        o0.y = s[1] * inv + h0.y;
        o0.z = s[2] * inv + h0.z;
        o0.w = s[3] * inv + h0.w;
        o1.x = s[4] * inv + h1.x;
        o1.y = s[5] * inv + h1.y;
        o1.z = s[6] * inv + h1.z;
        o1.w = s[7] * inv + h1.w;
        float* op = out + (size_t)node * 64 + f * 8;
        *(float4*)(op) = o0;
        *(float4*)(op + 4) = o1;
    }
}

extern "C" void kernel_launch(void* const* d_in, const int* in_sizes, int n_in,
                              void* d_out, int out_size, void* d_ws, size_t ws_size,
                              hipStream_t stream) {
    const float* x   = (const float*)d_in[0];
    const float* W1l = (const float*)d_in[1];
    const float* W1r = (const float*)d_in[2];
    const float* b1  = (const float*)d_in[3];
    const float* W2l = (const float*)d_in[4];
    const float* W2r = (const float*)d_in[5];
    const float* b2  = (const float*)d_in[6];
    const int*   ei  = (const int*)d_in[7];
    int N = in_sizes[0] / 128;
    int E = in_sizes[7] / 2;
    int NB = (N + 255) >> 8;
    int gb = (N + 127) / 128;
    int Np = gb * 128;      // padded node count for planes
    int spl = Np * 8;       // plane stride in shorts
    float* out = (float*)d_out;

    char* w = (char*)d_ws;
    size_t off = 0;
    auto alloc = [&](size_t bytes) -> char* {
        char* p = w + off;
        off += (bytes + 255) & ~(size_t)255;
        return p;
    };
    int*   row_ptr = (int*)alloc((size_t)(N + 1) * 4);
    int*   bcnt    = (int*)alloc((size_t)(NB + 1) * 4);
    int*   boff    = (int*)alloc((size_t)(NB + 1) * 4);
    int*   bcur    = (int*)alloc((size_t)(NB + 1) * 4);
    short* W1pH    = (short*)alloc(32768 * 2);
    short* W1pL    = (short*)alloc(32768 * 2);
    short* W2pH    = (short*)alloc(16384 * 2);
    short* W2pL    = (short*)alloc(16384 * 2);
    int*   col     = (int*)alloc((size_t)E * 4);
    short* xpH     = (short*)alloc((size_t)16 * spl * 2);   // 25.6 MB
    short* mpH     = (short*)alloc((size_t)16 * spl * 2);   // 25.6 MB
    short* mpL     = (short*)alloc((size_t)16 * spl * 2);   // 25.6 MB
    unsigned short* hl = (unsigned short*)alloc((size_t)N * 64 * 2);  // 12.8 MB
    char*  hrxb    = alloc((size_t)Np * 64 * 4);            // 25.6 MB shared
    // aliases (lifetime-disjoint):
    uint32* xb = (uint32*)hrxb;   // read until agg_mean; then dead
    float*  hr = (float*)hrxb;    // written by k_mgemm (after agg_mean)
    uint32* eb = (uint32*)hl;     // dead after k_bfinal; hl written by k_mgemm

    hipMemsetAsync(bcnt, 0, (size_t)NB * 4, stream);
    long n4 = (long)N * 32;
    long prep_items = n4 + 32768 + 16384;
    k_prep<<<(int)((prep_items + 255) / 256), 256, 0, stream>>>(
        x, xb, xpH, n4, spl, W1l, W1r, W2l, W2r, W1pH, W1pL, W2pH, W2pL);
    k_bcount<<<256, 256, 0, stream>>>(ei, E, NB, bcnt);
    k_bscan<<<1, 1024, 0, stream>>>(bcnt, NB, E, boff, bcur);
    k_bscatter<<<128, 256, 0, stream>>>(ei, E, NB, bcur, eb);
    k_bfinal<<<NB, 256, 0, stream>>>(eb, boff, row_ptr, col, N, E);

    int ab = (N + 3) / 4;
    k_agg_mean<<<ab, 256, 0, stream>>>(row_ptr, col, xb, mpH, mpL, N, spl);
    k_mgemm<<<gb, 256, 0, stream>>>(mpH, mpL, xpH, W1pH, W1pL, W2pH, W2pL,
                                    b1, b2, hl, hr, N, spl);
    k_agg_out<<<ab, 256, 0, stream>>>(row_ptr, col, (const uint32*)hl, hr, out, N);
}